// Round 2
// baseline (149.442 us; speedup 1.0000x reference)
//
#include <hip/hip_runtime.h>
#include <hip/hip_bf16.h>

// Spectral attention: B=2, N=50000, D=256, H=8, Dh=32, K_EIG=32, NUM_BANDS=3
// Key identity: Qf = E^T (x Wq^T + bq) = (E^T x) Wq^T + s * bq, s[k] = sum_n E[n,k]
// So the N-sized work is only: U = E^T x (read x once) and out = E @ out_freq (write out once).
// Filter-response band selection is done in FP64 to match the numpy (float64)
// reference: in fp32, (mx-mn)+1e-8f rounds to (mx-mn), making lam_max==1.0
// exactly and dropping the top band — a discrete branch flip worth 6e-2 absmax.

constexpr int D = 256;   // d_model

// ---------------------------------------------------------------- k_colsum
// partial column sums of E -> pS[block*32 + k]  (256 blocks)
__global__ __launch_bounds__(256) void k_colsum(const float* __restrict__ E,
                                                float* __restrict__ pS, int N) {
  int k = threadIdx.x & 31;
  int rg = threadIdx.x >> 5;               // 0..7
  int rs = (N + 255) >> 8;                 // rows per block
  int n0 = blockIdx.x * rs;
  int n1 = n0 + rs; if (n1 > N) n1 = N;
  float acc = 0.f;
  for (int n = n0 + rg; n < n1; n += 8) acc += E[(size_t)n * 32 + k];
  __shared__ float red[256];
  red[threadIdx.x] = acc;
  __syncthreads();
  if (threadIdx.x < 32) {
    float t = red[threadIdx.x];
#pragma unroll
    for (int i = 1; i < 8; ++i) t += red[i * 32 + threadIdx.x];
    pS[blockIdx.x * 32 + threadIdx.x] = t;
  }
}

// ---------------------------------------------------------------- k_partial
// pU[(b*nchunk + c)*32 + k][d] = sum_{n in chunk c} E[n,k] * x[b,n,d]
__global__ __launch_bounds__(256) void k_partial(const float* __restrict__ x,
                                                 const float* __restrict__ E,
                                                 float* __restrict__ pU,
                                                 int N, int nchunk, int rpc) {
  int blk = blockIdx.x;                    // b*nchunk + c
  int c = blk % nchunk;
  int b = blk / nchunk;
  int d = threadIdx.x;
  int n0 = c * rpc;
  int n1 = n0 + rpc; if (n1 > N) n1 = N;
  const float4* E4 = reinterpret_cast<const float4*>(E);
  const float* xp = x + (size_t)b * N * D + d;
  float acc[32];
#pragma unroll
  for (int k = 0; k < 32; ++k) acc[k] = 0.f;
#pragma unroll 4
  for (int n = n0; n < n1; ++n) {
    float xv = xp[(size_t)n * D];
    float4 e[8];
#pragma unroll
    for (int j = 0; j < 8; ++j) e[j] = E4[(size_t)n * 8 + j];
#pragma unroll
    for (int j = 0; j < 8; ++j) {
      acc[4 * j + 0] = fmaf(e[j].x, xv, acc[4 * j + 0]);
      acc[4 * j + 1] = fmaf(e[j].y, xv, acc[4 * j + 1]);
      acc[4 * j + 2] = fmaf(e[j].z, xv, acc[4 * j + 2]);
      acc[4 * j + 3] = fmaf(e[j].w, xv, acc[4 * j + 3]);
    }
  }
  float* o = pU + (size_t)blk * 32 * 256 + d;
#pragma unroll
  for (int k = 0; k < 32; ++k) o[k * 256] = acc[k];
}

// ---------------------------------------------------------------- k_reduce
// U[b,k,d] = sum_c pU[b,c,k,d]; grid = B*128 blocks, 64 elems/block, 4 sub-reducers
__global__ __launch_bounds__(256) void k_reduce(const float* __restrict__ pU,
                                                float* __restrict__ U, int nchunk) {
  int e = blockIdx.x * 64 + (threadIdx.x & 63);
  int sub = threadIdx.x >> 6;              // 0..3
  int b = e >> 13;                         // / 8192
  int kd = e & 8191;
  const float* p = pU + (size_t)b * nchunk * 8192 + kd;
  float acc = 0.f;
  for (int c = sub; c < nchunk; c += 4) acc += p[(size_t)c * 8192];
  __shared__ float red[256];
  red[threadIdx.x] = acc;
  __syncthreads();
  if (threadIdx.x < 64)
    U[e] = (red[threadIdx.x] + red[threadIdx.x + 64]) +
           (red[threadIdx.x + 128] + red[threadIdx.x + 192]);
}

// ---------------------------------------------------------------- k_project
// per (b,k): Qfg[b,k,hd] = (U[b,k,:] . Wq[hd,:] + bq[hd]*s[k]) * g[k,h]; same K,V
__global__ __launch_bounds__(256) void k_project(
    const float* __restrict__ U, const float* __restrict__ pS,
    const float* __restrict__ Wq, const float* __restrict__ bq,
    const float* __restrict__ Wk, const float* __restrict__ bk,
    const float* __restrict__ Wv, const float* __restrict__ bv,
    const float* __restrict__ ev, const float* __restrict__ bb,
    const float* __restrict__ fw,
    float* __restrict__ Qfg, float* __restrict__ Kfg, float* __restrict__ Vfg) {
  int blk = blockIdx.x;                    // b*32 + k
  int k = blk & 31;
  int t = threadIdx.x;                     // hd output
  __shared__ __align__(16) float u[256];
  __shared__ float red[256];
  u[t] = U[(size_t)blk * 256 + t];
  red[t] = pS[t * 32 + k];
  __syncthreads();
#pragma unroll
  for (int off = 128; off > 0; off >>= 1) {
    if (t < off) red[t] += red[t + off];
    __syncthreads();
  }
  float sk = red[0];

  // filter response g for (h = t>>5, k) — FP64 to match numpy ref semantics
  float mnf = ev[0], mxf = ev[0];
#pragma unroll
  for (int i = 1; i < 32; ++i) { float v = ev[i]; mnf = fminf(mnf, v); mxf = fmaxf(mxf, v); }
  double mn = (double)mnf, mx = (double)mxf;
  double lam = ((double)ev[k] - mn) / (mx - mn + 1e-8);
  int h = t >> 5;
  float g = 0.f;
#pragma unroll
  for (int i = 0; i < 3; ++i) {
    double lo = (double)bb[h * 4 + i], hi = (double)bb[h * 4 + i + 1];
    if (lam >= lo && lam < hi) g = fw[(h * 3 + i) * 32 + k];
  }

  const float4* u4 = reinterpret_cast<const float4*>(u);
  const float4* wq4 = reinterpret_cast<const float4*>(Wq) + (size_t)t * 64;
  const float4* wk4 = reinterpret_cast<const float4*>(Wk) + (size_t)t * 64;
  const float4* wv4 = reinterpret_cast<const float4*>(Wv) + (size_t)t * 64;
  float aq = 0.f, ak = 0.f, av = 0.f;
#pragma unroll 4
  for (int j = 0; j < 64; ++j) {
    float4 uv = u4[j];
    float4 q = wq4[j], kk = wk4[j], vv = wv4[j];
    aq = fmaf(uv.x, q.x, aq);  aq = fmaf(uv.y, q.y, aq);
    aq = fmaf(uv.z, q.z, aq);  aq = fmaf(uv.w, q.w, aq);
    ak = fmaf(uv.x, kk.x, ak); ak = fmaf(uv.y, kk.y, ak);
    ak = fmaf(uv.z, kk.z, ak); ak = fmaf(uv.w, kk.w, ak);
    av = fmaf(uv.x, vv.x, av); av = fmaf(uv.y, vv.y, av);
    av = fmaf(uv.z, vv.z, av); av = fmaf(uv.w, vv.w, av);
  }
  Qfg[(size_t)blk * 256 + t] = (aq + bq[t] * sk) * g;
  Kfg[(size_t)blk * 256 + t] = (ak + bk[t] * sk) * g;
  Vfg[(size_t)blk * 256 + t] = (av + bv[t] * sk) * g;
}

// ---------------------------------------------------------------- k_attn
// per (b,h): scores = (Qfg Kfg^T)/sqrt(Dh); softmax over l; of = attn @ Vfg
__global__ __launch_bounds__(1024) void k_attn(const float* __restrict__ Qfg,
                                               const float* __restrict__ Kfg,
                                               const float* __restrict__ Vfg,
                                               float* __restrict__ of) {
  int blk = blockIdx.x;                    // b*8 + h
  int b = blk >> 3, h = blk & 7;
  int tid = threadIdx.x;
  int row = tid >> 5, col = tid & 31;
  __shared__ float Q[32][33], Kt[32][33], V[32][33], A[32][33];
  size_t base = (size_t)b * 32 * 256 + h * 32;
  Q[row][col]  = Qfg[base + row * 256 + col];
  Kt[row][col] = Kfg[base + row * 256 + col];
  V[row][col]  = Vfg[base + row * 256 + col];
  __syncthreads();
  float sc = 0.f;
#pragma unroll
  for (int d0 = 0; d0 < 32; ++d0) sc = fmaf(Q[row][d0], Kt[col][d0], sc);
  sc *= 0.17677669529663687f;              // 1/sqrt(32)
  float m = sc;
#pragma unroll
  for (int o = 16; o > 0; o >>= 1) m = fmaxf(m, __shfl_xor(m, o, 32));
  float p = expf(sc - m);
  float su = p;
#pragma unroll
  for (int o = 16; o > 0; o >>= 1) su += __shfl_xor(su, o, 32);
  A[row][col] = p / su;
  __syncthreads();
  float o_ = 0.f;
#pragma unroll
  for (int l = 0; l < 32; ++l) o_ = fmaf(A[row][l], V[l][col], o_);
  of[base + row * 256 + col] = o_;
}

// ---------------------------------------------------------------- k_expand
// out[b,n,hd] = sum_k E[n,k] * of[b,k,hd]
__global__ __launch_bounds__(256) void k_expand(const float* __restrict__ E,
                                                const float* __restrict__ of,
                                                float* __restrict__ out,
                                                int N, int nb5) {
  int blk = blockIdx.x;
  int b = blk / nb5;
  int br = blk % nb5;
  int t = threadIdx.x;
  float ofr[32];
#pragma unroll
  for (int k = 0; k < 32; ++k) ofr[k] = of[(size_t)(b * 32 + k) * 256 + t];
  int n0 = br * 64;
  int n1 = n0 + 64; if (n1 > N) n1 = N;
  const float4* E4 = reinterpret_cast<const float4*>(E);
  float* op = out + (size_t)b * N * 256 + t;
#pragma unroll 2
  for (int n = n0; n < n1; ++n) {
    float4 e[8];
#pragma unroll
    for (int j = 0; j < 8; ++j) e[j] = E4[(size_t)n * 8 + j];
    float acc = 0.f;
#pragma unroll
    for (int j = 0; j < 8; ++j) {
      acc = fmaf(e[j].x, ofr[4 * j + 0], acc);
      acc = fmaf(e[j].y, ofr[4 * j + 1], acc);
      acc = fmaf(e[j].z, ofr[4 * j + 2], acc);
      acc = fmaf(e[j].w, ofr[4 * j + 3], acc);
    }
    op[(size_t)n * 256] = acc;
  }
}

// ---------------------------------------------------------------- launch
extern "C" void kernel_launch(void* const* d_in, const int* in_sizes, int n_in,
                              void* d_out, int out_size, void* d_ws, size_t ws_size,
                              hipStream_t stream) {
  const float* x  = (const float*)d_in[0];
  const float* E  = (const float*)d_in[1];
  const float* ev = (const float*)d_in[2];
  const float* Wq = (const float*)d_in[3];
  const float* bq = (const float*)d_in[4];
  const float* Wk = (const float*)d_in[5];
  const float* bk = (const float*)d_in[6];
  const float* Wv = (const float*)d_in[7];
  const float* bv = (const float*)d_in[8];
  const float* bb = (const float*)d_in[9];
  const float* fw = (const float*)d_in[10];
  float* out = (float*)d_out;
  float* ws  = (float*)d_ws;

  const int N = in_sizes[1] / 32;          // 50000
  const int B = in_sizes[0] / (N * 256);   // 2

  // workspace layout (floats)
  float* U   = ws;                         // B*32*256 = 16384
  float* Qfg = ws + 16384;
  float* Kfg = ws + 32768;
  float* Vfg = ws + 49152;
  float* of  = ws + 65536;
  float* pS  = ws + 81920;                 // 256*32 = 8192
  float* pU  = ws + 90112;                 // B*nchunk*32*256

  int nchunk = 256;
  while (nchunk > 32 &&
         (90112 + (size_t)B * nchunk * 8192) * sizeof(float) > ws_size)
    nchunk >>= 1;
  int rpc = (N + nchunk - 1) / nchunk;

  k_colsum<<<256, 256, 0, stream>>>(E, pS, N);
  k_partial<<<B * nchunk, 256, 0, stream>>>(x, E, pU, N, nchunk, rpc);
  k_reduce<<<B * 128, 256, 0, stream>>>(pU, U, nchunk);
  k_project<<<B * 32, 256, 0, stream>>>(U, pS, Wq, bq, Wk, bk, Wv, bv,
                                        ev, bb, fw, Qfg, Kfg, Vfg);
  k_attn<<<B * 8, 1024, 0, stream>>>(Qfg, Kfg, Vfg, of);
  int nb5 = (N + 63) / 64;
  k_expand<<<B * nb5, 256, 0, stream>>>(E, of, out, N, nb5);
}